// Round 9
// baseline (520.000 us; speedup 1.0000x reference)
//
#include <hip/hip_runtime.h>
#include <hip/hip_bf16.h>

// QuanvolutionGraphQLClassifier — f32 in/out. ONE kernel, 1024 blocks.
// Proven pieces: H-bilinear measurement (R4+, absmax<=1.0), ws-flag
// release/acquire across blocks (R7, correct), spill-free big-grid fused
// structure (R8, VALUBusy 78%). New: W2 fold done ONCE by blocks 0..9 with
// W row staged in LDS (fold is LDS+VALU only), instead of per-sample
// adjacency (R8's 27x work mistake) or a separate producer kernel (R2-R6).
//
// Math: e_d = wA . H_d . wB per patch; W2[k,4m+d] = sum_n adj(n,m) W[k,4n+d];
// logits[b,k] = sum_p meas[b,p,:] . W2[k,4p..] + bias[k]; log_softmax.
// Flags: d_ws is re-poisoned 0xAA before every replay => 0xAAAAAAAA != MAGIC,
// so no init kernel needed; writers store MAGIC with device-scope release.

#define NP 196
#define MAGIC 0x13572468u

__device__ __forceinline__ float quad3(const float* H, const float* wa,
                                       const float* wb) {
  return wa[0] * (H[0] * wb[0] + H[1] * wb[1] + H[2] * wb[2]) +
         wa[1] * (H[3] * wb[0] + H[4] * wb[1] + H[5] * wb[2]) +
         wa[2] * (H[6] * wb[0] + H[7] * wb[1] + H[8] * wb[2]);
}

// Builds the full H[36] (A: 0..17, B: 18..35) — wave-uniform, all regs.
__device__ __forceinline__ void build_H_all(const float* __restrict__ qp,
                                            float* __restrict__ H) {
  float qc[6], qs[6];
#pragma unroll
  for (int i = 0; i < 6; ++i) __sincosf(0.5f * qp[i], &qs[i], &qc[i]);
#pragma unroll
  for (int sub = 0; sub < 2; ++sub) {
    float Mr[4][4] = {}, Mi[4][4] = {};
    if (sub == 0) {
      // U_A = RY(q4,w0) * CNOT01 * RY(q1,w1) * RX(q0,w0); index = 2*b0 + b1
      Mr[0][0] = Mr[1][1] = Mr[2][2] = Mr[3][3] = qc[0];  // RX(q0) on w0
      Mi[0][2] = Mi[2][0] = Mi[1][3] = Mi[3][1] = -qs[0];
#pragma unroll
      for (int j = 0; j < 4; ++j) {  // RY(q1) on w1: rows (0,1),(2,3)
        float a, b;
        a = Mr[0][j]; b = Mr[1][j]; Mr[0][j] = qc[1]*a - qs[1]*b; Mr[1][j] = qs[1]*a + qc[1]*b;
        a = Mi[0][j]; b = Mi[1][j]; Mi[0][j] = qc[1]*a - qs[1]*b; Mi[1][j] = qs[1]*a + qc[1]*b;
        a = Mr[2][j]; b = Mr[3][j]; Mr[2][j] = qc[1]*a - qs[1]*b; Mr[3][j] = qs[1]*a + qc[1]*b;
        a = Mi[2][j]; b = Mi[3][j]; Mi[2][j] = qc[1]*a - qs[1]*b; Mi[3][j] = qs[1]*a + qc[1]*b;
      }
#pragma unroll
      for (int j = 0; j < 4; ++j) {  // CNOT(0,1): swap rows 2,3
        float r = Mr[2][j]; Mr[2][j] = Mr[3][j]; Mr[3][j] = r;
        float q = Mi[2][j]; Mi[2][j] = Mi[3][j]; Mi[3][j] = q;
      }
#pragma unroll
      for (int j = 0; j < 4; ++j) {  // RY(q4) on w0: rows (0,2),(1,3)
        float a, b;
        a = Mr[0][j]; b = Mr[2][j]; Mr[0][j] = qc[4]*a - qs[4]*b; Mr[2][j] = qs[4]*a + qc[4]*b;
        a = Mi[0][j]; b = Mi[2][j]; Mi[0][j] = qc[4]*a - qs[4]*b; Mi[2][j] = qs[4]*a + qc[4]*b;
        a = Mr[1][j]; b = Mr[3][j]; Mr[1][j] = qc[4]*a - qs[4]*b; Mr[3][j] = qs[4]*a + qc[4]*b;
        a = Mi[1][j]; b = Mi[3][j]; Mi[1][j] = qc[4]*a - qs[4]*b; Mi[3][j] = qs[4]*a + qc[4]*b;
      }
    } else {
      // U_B = RZ(q5,w3) * CNOT23 * RX(q3,w3) * RZ(q2,w2); index = 2*b2 + b3
      Mr[0][0] = Mr[1][1] = Mr[2][2] = Mr[3][3] = qc[2];  // RZ(q2) on w2
      Mi[0][0] = Mi[1][1] = -qs[2]; Mi[2][2] = Mi[3][3] = qs[2];
#pragma unroll
      for (int j = 0; j < 4; ++j) {  // RX(q3) on w3: rows (0,1),(2,3)
        float ra, ia, rb, ib;
        ra = Mr[0][j]; ia = Mi[0][j]; rb = Mr[1][j]; ib = Mi[1][j];
        Mr[0][j] = qc[3]*ra + qs[3]*ib;  Mi[0][j] = qc[3]*ia - qs[3]*rb;
        Mr[1][j] = qc[3]*rb + qs[3]*ia;  Mi[1][j] = qc[3]*ib - qs[3]*ra;
        ra = Mr[2][j]; ia = Mi[2][j]; rb = Mr[3][j]; ib = Mi[3][j];
        Mr[2][j] = qc[3]*ra + qs[3]*ib;  Mi[2][j] = qc[3]*ia - qs[3]*rb;
        Mr[3][j] = qc[3]*rb + qs[3]*ia;  Mi[3][j] = qc[3]*ib - qs[3]*ra;
      }
#pragma unroll
      for (int j = 0; j < 4; ++j) {  // CNOT(2,3): swap rows 2,3
        float r = Mr[2][j]; Mr[2][j] = Mr[3][j]; Mr[3][j] = r;
        float q = Mi[2][j]; Mi[2][j] = Mi[3][j]; Mi[3][j] = q;
      }
#pragma unroll
      for (int r = 0; r < 4; ++r) {  // RZ(q5) on w3: rows 0,2 *(c5-is5); 1,3 *(c5+is5)
        float sg = (r & 1) ? 1.0f : -1.0f;
#pragma unroll
        for (int j = 0; j < 4; ++j) {
          float re = Mr[r][j], im = Mi[r][j];
          Mr[r][j] = qc[5] * re - sg * qs[5] * im;
          Mi[r][j] = qc[5] * im + sg * qs[5] * re;
        }
      }
    }
    // G_d[j][k] = sum_i sigma_i (Re U_ij Re U_ik + Im U_ij Im U_ik)
#pragma unroll
    for (int d = 0; d < 2; ++d) {
      float G[4][4];
#pragma unroll
      for (int j = 0; j < 4; ++j)
#pragma unroll
        for (int k = 0; k < 4; ++k) {
          float g = 0.0f;
#pragma unroll
          for (int i = 0; i < 4; ++i) {
            float sg = (d == 0) ? ((i < 2) ? 1.f : -1.f)
                                : (((i & 1) == 0) ? 1.f : -1.f);
            g += sg * (Mr[i][j] * Mr[i][k] + Mi[i][j] * Mi[i][k]);
          }
          G[j][k] = g;
        }
      float* Hd = H + sub * 18 + d * 9;
      Hd[0] = G[0][0];       Hd[1] = 2.f * G[0][1];               Hd[2] = G[1][1];
      Hd[3] = 2.f * G[0][2]; Hd[4] = 2.f * (G[0][3] + G[1][2]);   Hd[5] = 2.f * G[1][3];
      Hd[6] = G[2][2];       Hd[7] = 2.f * G[2][3];               Hd[8] = G[3][3];
    }
  }
}

// Pauli-Z expectations of patch p of image xb, via the H bilinear forms.
__device__ __forceinline__ void meas_patch(const float* __restrict__ xb, int p,
                                           const float* __restrict__ H,
                                           float* e) {
  int i = p / 14, j = p - 14 * i;
  float2 top = *(const float2*)(xb + 56 * i + 2 * j);
  float2 bot = *(const float2*)(xb + 56 * i + 28 + 2 * j);
  float c0, s0, c1, s1, c2, s2, c3, s3;
  __sincosf(0.5f * top.x, &s0, &c0);
  __sincosf(0.5f * top.y, &s1, &c1);
  __sincosf(0.5f * bot.x, &s2, &c2);
  __sincosf(0.5f * bot.y, &s3, &c3);
  float wA0[3] = {c0 * c0, c0 * s0, s0 * s0};
  float wA1[3] = {c1 * c1, c1 * s1, s1 * s1};
  float wB0[3] = {c2 * c2, c2 * s2, s2 * s2};
  float wB1[3] = {c3 * c3, c3 * s3, s3 * s3};
  e[0] = quad3(H, wA0, wA1);
  e[1] = quad3(H + 9, wA0, wA1);
  e[2] = quad3(H + 18, wB0, wB1);
  e[3] = quad3(H + 27, wB0, wB1);
}

__global__ __launch_bounds__(256, 1) void k_fused(
    const float* __restrict__ x, const float* __restrict__ qp,
    const float* __restrict__ W, const float* __restrict__ bias,
    float* __restrict__ out, float* __restrict__ W2,
    unsigned int* __restrict__ flags, int Bsz) {
  __shared__ float4 us[NP];     // sample-0 measurements, normalized (writers)
  __shared__ float Wlds[784];   // W row k = blockIdx.x (writers)
  int t = threadIdx.x, wv = t >> 6, lane = t & 63;
  int bid = blockIdx.x;
  int b = bid * 4 + wv;
  bool alive = (b < Bsz);

  float H[36];
  build_H_all(qp, H);  // wave-uniform, registers only

  // ---- writer blocks 0..9: fold adjacency into W2 row bid ----------------
  if (bid < 10) {
    if (wv == 0) {  // wave 0 measures sample 0, normalized
#pragma unroll
      for (int r = 0; r < 4; ++r) {
        int p = lane + 64 * r;
        if (p < NP) {
          float e[4];
          meas_patch(x, p, H, e);
          float n = sqrtf(e[0]*e[0] + e[1]*e[1] + e[2]*e[2] + e[3]*e[3]) + 1e-12f;
          float rn = 1.0f / n;
          us[p] = make_float4(e[0]*rn, e[1]*rn, e[2]*rn, e[3]*rn);
        }
      }
    }
    for (int i = t; i < 784; i += 256) Wlds[i] = W[bid * 784 + i];
    __syncthreads();  // block-uniform branch: only writer blocks hit this
    if (t < NP) {
      int m = t;
      float4 um = us[m];
      float a0 = 0.f, a1 = 0.f, a2 = 0.f, a3 = 0.f;
      const float4* W4 = (const float4*)Wlds;
#pragma unroll 4
      for (int n = 0; n < NP; ++n) {
        float4 un = us[n];   // uniform n -> LDS broadcast
        float dot = um.x*un.x + um.y*un.y + um.z*un.z + um.w*un.w;
        float w = (dot >= 0.9f) ? 1.0f : ((dot >= 0.5f) ? 0.5f : 0.0f);
        float4 wn = W4[n];
        a0 += w * wn.x; a1 += w * wn.y; a2 += w * wn.z; a3 += w * wn.w;
      }
      float* dst = W2 + bid * 784 + 4 * m;
      dst[0] = a0; dst[1] = a1; dst[2] = a2; dst[3] = a3;
    }
    __threadfence();   // this thread's W2 stores device-visible
    __syncthreads();   // all threads' stores fenced before the flag
    if (t == 0)
      __hip_atomic_store(&flags[bid], MAGIC, __ATOMIC_RELEASE,
                         __HIP_MEMORY_SCOPE_AGENT);
  }

  // ---- all blocks: measure own sample into registers (overlaps writers) --
  const float* xb = x + (size_t)(alive ? b : 0) * 784;
  float ev[16];
#pragma unroll
  for (int r = 0; r < 4; ++r) {
    int p = lane + 64 * r;
    if (p < NP) {
      float e[4];
      meas_patch(xb, p, H, e);
      ev[4*r+0] = e[0]; ev[4*r+1] = e[1]; ev[4*r+2] = e[2]; ev[4*r+3] = e[3];
    } else {
      ev[4*r+0] = ev[4*r+1] = ev[4*r+2] = ev[4*r+3] = 0.f;
    }
  }

  // ---- acquire all 10 W2 rows (R7-proven pattern) ----
  if (lane == 0) {
#pragma unroll 1
    for (int i = 0; i < 10; ++i) {
      while (__hip_atomic_load(&flags[i], __ATOMIC_ACQUIRE,
                               __HIP_MEMORY_SCOPE_AGENT) != MAGIC)
        __builtin_amdgcn_s_sleep(8);
    }
  }
  __threadfence();  // order W2 loads after the acquire, wave-wide

  // ---- logits = meas . W2^T, butterfly reduce, log_softmax ----
  float acc[10];
#pragma unroll
  for (int k = 0; k < 10; ++k) acc[k] = 0.0f;
#pragma unroll
  for (int r = 0; r < 4; ++r) {
    int p = lane + 64 * r;
    if (p < NP) {
#pragma unroll
      for (int k = 0; k < 10; ++k) {
        float4 w4 = *(const float4*)(W2 + k * 784 + 4 * p);
        acc[k] += ev[4*r+0] * w4.x + ev[4*r+1] * w4.y +
                  ev[4*r+2] * w4.z + ev[4*r+3] * w4.w;
      }
    }
  }
#pragma unroll
  for (int k = 0; k < 10; ++k)
#pragma unroll
    for (int off = 32; off; off >>= 1) acc[k] += __shfl_xor(acc[k], off);

  if (!alive) return;
  float lg[10], mx = -1e30f;
#pragma unroll
  for (int k = 0; k < 10; ++k) { lg[k] = acc[k] + bias[k]; mx = fmaxf(mx, lg[k]); }
  float sm = 0.0f;
#pragma unroll
  for (int k = 0; k < 10; ++k) sm += __expf(lg[k] - mx);
  float lse = mx + __logf(sm);
  if (lane < 10) {
    float sel = lg[0];
#pragma unroll
    for (int k = 1; k < 10; ++k) sel = (lane == k) ? lg[k] : sel;
    out[(size_t)b * 10 + lane] = sel - lse;
  }
}

extern "C" void kernel_launch(void* const* d_in, const int* in_sizes, int n_in,
                              void* d_out, int out_size, void* d_ws, size_t ws_size,
                              hipStream_t stream) {
  const float* x  = (const float*)d_in[0];  // (B,1,28,28) f32
  const float* qp = (const float*)d_in[1];  // (6,) f32
  const float* W  = (const float*)d_in[2];  // (10,784) f32
  const float* bi = (const float*)d_in[3];  // (10,) f32
  float* out = (float*)d_out;               // (B,10) f32

  int Bsz = in_sizes[0] / 784;              // 4096

  float* W2 = (float*)d_ws;                          // 7840 f32
  unsigned int* flags = (unsigned int*)(W2 + 7840);  // 10 u32, poison != MAGIC

  int grid = (Bsz + 3) / 4;                 // 1024 blocks, 1 sample per wave
  k_fused<<<grid, 256, 0, stream>>>(x, qp, W, bi, out, W2, flags, Bsz);
}

// Round 10
// 121.658 us; speedup vs baseline: 4.2743x; 4.2743x over previous
//
#include <hip/hip_runtime.h>
#include <hip/hip_bf16.h>

// QuanvolutionGraphQLClassifier — f32 in/out. ONE kernel, NO cross-block sync
// (R7/R9: device-scope flag polling = 320/507 us catastrophe), NO small-grid
// producer (R2-R6: ~40 us cold-icache stall at 1 wave/CU). Structure: 256
// blocks x 1024 threads (16 samples/block, 1 block/CU); each block redundantly
// folds adjacency into W2 in LDS (1.54M FMA/block ~ 6 us at VALU peak), then
// its 16 waves consume it. Redundant fold is the price of independence.
//
// Math (verified R4+): e_d = wA . H_d . wB per patch; adjacency from
// normalized sample-0 meas (division-free thresholds); W2[k,4m+d] =
// sum_n w(n,m) W[k,4n+d]; logits = meas . W2^T + bias; log_softmax.

#define NP 196

__device__ __forceinline__ float quad3(const float* H, const float* wa,
                                       const float* wb) {
  return wa[0] * (H[0] * wb[0] + H[1] * wb[1] + H[2] * wb[2]) +
         wa[1] * (H[3] * wb[0] + H[4] * wb[1] + H[5] * wb[2]) +
         wa[2] * (H[6] * wb[0] + H[7] * wb[1] + H[8] * wb[2]);
}

// Builds the full H[36] (A: 0..17, B: 18..35) — wave-uniform, all regs.
__device__ __forceinline__ void build_H_all(const float* __restrict__ qp,
                                            float* __restrict__ H) {
  float qc[6], qs[6];
#pragma unroll
  for (int i = 0; i < 6; ++i) __sincosf(0.5f * qp[i], &qs[i], &qc[i]);
#pragma unroll
  for (int sub = 0; sub < 2; ++sub) {
    float Mr[4][4] = {}, Mi[4][4] = {};
    if (sub == 0) {
      // U_A = RY(q4,w0) * CNOT01 * RY(q1,w1) * RX(q0,w0); index = 2*b0 + b1
      Mr[0][0] = Mr[1][1] = Mr[2][2] = Mr[3][3] = qc[0];  // RX(q0) on w0
      Mi[0][2] = Mi[2][0] = Mi[1][3] = Mi[3][1] = -qs[0];
#pragma unroll
      for (int j = 0; j < 4; ++j) {  // RY(q1) on w1: rows (0,1),(2,3)
        float a, b;
        a = Mr[0][j]; b = Mr[1][j]; Mr[0][j] = qc[1]*a - qs[1]*b; Mr[1][j] = qs[1]*a + qc[1]*b;
        a = Mi[0][j]; b = Mi[1][j]; Mi[0][j] = qc[1]*a - qs[1]*b; Mi[1][j] = qs[1]*a + qc[1]*b;
        a = Mr[2][j]; b = Mr[3][j]; Mr[2][j] = qc[1]*a - qs[1]*b; Mr[3][j] = qs[1]*a + qc[1]*b;
        a = Mi[2][j]; b = Mi[3][j]; Mi[2][j] = qc[1]*a - qs[1]*b; Mi[3][j] = qs[1]*a + qc[1]*b;
      }
#pragma unroll
      for (int j = 0; j < 4; ++j) {  // CNOT(0,1): swap rows 2,3
        float r = Mr[2][j]; Mr[2][j] = Mr[3][j]; Mr[3][j] = r;
        float q = Mi[2][j]; Mi[2][j] = Mi[3][j]; Mi[3][j] = q;
      }
#pragma unroll
      for (int j = 0; j < 4; ++j) {  // RY(q4) on w0: rows (0,2),(1,3)
        float a, b;
        a = Mr[0][j]; b = Mr[2][j]; Mr[0][j] = qc[4]*a - qs[4]*b; Mr[2][j] = qs[4]*a + qc[4]*b;
        a = Mi[0][j]; b = Mi[2][j]; Mi[0][j] = qc[4]*a - qs[4]*b; Mi[2][j] = qs[4]*a + qc[4]*b;
        a = Mr[1][j]; b = Mr[3][j]; Mr[1][j] = qc[4]*a - qs[4]*b; Mr[3][j] = qs[4]*a + qc[4]*b;
        a = Mi[1][j]; b = Mi[3][j]; Mi[1][j] = qc[4]*a - qs[4]*b; Mi[3][j] = qs[4]*a + qc[4]*b;
      }
    } else {
      // U_B = RZ(q5,w3) * CNOT23 * RX(q3,w3) * RZ(q2,w2); index = 2*b2 + b3
      Mr[0][0] = Mr[1][1] = Mr[2][2] = Mr[3][3] = qc[2];  // RZ(q2) on w2
      Mi[0][0] = Mi[1][1] = -qs[2]; Mi[2][2] = Mi[3][3] = qs[2];
#pragma unroll
      for (int j = 0; j < 4; ++j) {  // RX(q3) on w3: rows (0,1),(2,3)
        float ra, ia, rb, ib;
        ra = Mr[0][j]; ia = Mi[0][j]; rb = Mr[1][j]; ib = Mi[1][j];
        Mr[0][j] = qc[3]*ra + qs[3]*ib;  Mi[0][j] = qc[3]*ia - qs[3]*rb;
        Mr[1][j] = qc[3]*rb + qs[3]*ia;  Mi[1][j] = qc[3]*ib - qs[3]*ra;
        ra = Mr[2][j]; ia = Mi[2][j]; rb = Mr[3][j]; ib = Mi[3][j];
        Mr[2][j] = qc[3]*ra + qs[3]*ib;  Mi[2][j] = qc[3]*ia - qs[3]*rb;
        Mr[3][j] = qc[3]*rb + qs[3]*ia;  Mi[3][j] = qc[3]*ib - qs[3]*ra;
      }
#pragma unroll
      for (int j = 0; j < 4; ++j) {  // CNOT(2,3): swap rows 2,3
        float r = Mr[2][j]; Mr[2][j] = Mr[3][j]; Mr[3][j] = r;
        float q = Mi[2][j]; Mi[2][j] = Mi[3][j]; Mi[3][j] = q;
      }
#pragma unroll
      for (int r = 0; r < 4; ++r) {  // RZ(q5) on w3: rows 0,2 *(c5-is5); 1,3 *(c5+is5)
        float sg = (r & 1) ? 1.0f : -1.0f;
#pragma unroll
        for (int j = 0; j < 4; ++j) {
          float re = Mr[r][j], im = Mi[r][j];
          Mr[r][j] = qc[5] * re - sg * qs[5] * im;
          Mi[r][j] = qc[5] * im + sg * qs[5] * re;
        }
      }
    }
    // G_d[j][k] = sum_i sigma_i (Re U_ij Re U_ik + Im U_ij Im U_ik)
#pragma unroll
    for (int d = 0; d < 2; ++d) {
      float G[4][4];
#pragma unroll
      for (int j = 0; j < 4; ++j)
#pragma unroll
        for (int k = 0; k < 4; ++k) {
          float g = 0.0f;
#pragma unroll
          for (int i = 0; i < 4; ++i) {
            float sg = (d == 0) ? ((i < 2) ? 1.f : -1.f)
                                : (((i & 1) == 0) ? 1.f : -1.f);
            g += sg * (Mr[i][j] * Mr[i][k] + Mi[i][j] * Mi[i][k]);
          }
          G[j][k] = g;
        }
      float* Hd = H + sub * 18 + d * 9;
      Hd[0] = G[0][0];       Hd[1] = 2.f * G[0][1];               Hd[2] = G[1][1];
      Hd[3] = 2.f * G[0][2]; Hd[4] = 2.f * (G[0][3] + G[1][2]);   Hd[5] = 2.f * G[1][3];
      Hd[6] = G[2][2];       Hd[7] = 2.f * G[2][3];               Hd[8] = G[3][3];
    }
  }
}

// Pauli-Z expectations of patch p of image xb, via the H bilinear forms.
__device__ __forceinline__ void meas_patch(const float* __restrict__ xb, int p,
                                           const float* __restrict__ H,
                                           float* e) {
  int i = p / 14, j = p - 14 * i;
  float2 top = *(const float2*)(xb + 56 * i + 2 * j);
  float2 bot = *(const float2*)(xb + 56 * i + 28 + 2 * j);
  float c0, s0, c1, s1, c2, s2, c3, s3;
  __sincosf(0.5f * top.x, &s0, &c0);
  __sincosf(0.5f * top.y, &s1, &c1);
  __sincosf(0.5f * bot.x, &s2, &c2);
  __sincosf(0.5f * bot.y, &s3, &c3);
  float wA0[3] = {c0 * c0, c0 * s0, s0 * s0};
  float wA1[3] = {c1 * c1, c1 * s1, s1 * s1};
  float wB0[3] = {c2 * c2, c2 * s2, s2 * s2};
  float wB1[3] = {c3 * c3, c3 * s3, s3 * s3};
  e[0] = quad3(H, wA0, wA1);
  e[1] = quad3(H + 9, wA0, wA1);
  e[2] = quad3(H + 18, wB0, wB1);
  e[3] = quad3(H + 27, wB0, wB1);
}

__global__ __launch_bounds__(1024, 1) void k_fused(
    const float* __restrict__ x, const float* __restrict__ qp,
    const float* __restrict__ W, const float* __restrict__ bias,
    float* __restrict__ out, int Bsz) {
  __shared__ float Hl[36];
  __shared__ float4 us[NP];                 // sample-0 meas, normalized
  __shared__ unsigned char A[NP * 198];     // code {0,1,2}; w = 0.5*code; 38.8 KB
  __shared__ float W2s[10 * 784];           // folded weights; 31.4 KB
  int t = threadIdx.x, wv = t >> 6, lane = t & 63;
  int b = blockIdx.x * 16 + wv;
  bool alive = (b < Bsz);

  // ---- wave 0: H -> LDS, sample-0 normalized meas -> LDS ----
  if (wv == 0) {
    float H0[36];
    build_H_all(qp, H0);
    if (lane == 0) {
#pragma unroll
      for (int i = 0; i < 36; ++i) Hl[i] = H0[i];  // constant reg indices
    }
#pragma unroll
    for (int r = 0; r < 4; ++r) {
      int p = lane + 64 * r;
      if (p < NP) {
        float e[4];
        meas_patch(x, p, H0, e);
        float n = sqrtf(e[0]*e[0] + e[1]*e[1] + e[2]*e[2] + e[3]*e[3]) + 1e-12f;
        float rn = 1.0f / n;
        us[p] = make_float4(e[0]*rn, e[1]*rn, e[2]*rn, e[3]*rn);
      }
    }
  }
  __syncthreads();

  // ---- phase A: classify adjacency once -> packed u8 (code = 2w) ----
  for (int o = t; o < NP * NP; o += 1024) {
    int m = o / NP, n = o - m * NP;
    float4 a = us[m], c = us[n];
    float dot = a.x * c.x + a.y * c.y + a.z * c.z + a.w * c.w;
    unsigned char code = (dot >= 0.9f) ? 2 : ((dot >= 0.5f) ? 1 : 0);
    A[m * 198 + n] = code;
  }
  __syncthreads();

  // ---- phase B: fold into W2s[k][4m+d] (W reads wave-uniform -> L1 bcast) --
  for (int o = t; o < 10 * NP; o += 1024) {
    int k = o / NP, m = o - k * NP;
    const float4* Wk = (const float4*)(W + k * 784);
    const unsigned char* Am = A + m * 198;
    float4 acc = make_float4(0.f, 0.f, 0.f, 0.f);
#pragma unroll 4
    for (int n = 0; n < NP; ++n) {
      float w = 0.5f * (float)Am[n];
      float4 w4 = Wk[n];
      acc.x += w * w4.x; acc.y += w * w4.y;
      acc.z += w * w4.z; acc.w += w * w4.w;
    }
    *(float4*)(W2s + k * 784 + 4 * m) = acc;
  }
  __syncthreads();

  // ---- per wave: own-sample meas (regs), W2 dot, reduce, log_softmax ----
  float H[36];
#pragma unroll
  for (int i = 0; i < 36; ++i) H[i] = Hl[i];
  const float* xb = x + (size_t)(alive ? b : 0) * 784;
  float ev[16];
#pragma unroll
  for (int r = 0; r < 4; ++r) {
    int p = lane + 64 * r;
    if (p < NP) {
      float e[4];
      meas_patch(xb, p, H, e);
      ev[4*r+0] = e[0]; ev[4*r+1] = e[1]; ev[4*r+2] = e[2]; ev[4*r+3] = e[3];
    } else {
      ev[4*r+0] = ev[4*r+1] = ev[4*r+2] = ev[4*r+3] = 0.f;
    }
  }
  float acc[10];
#pragma unroll
  for (int k = 0; k < 10; ++k) acc[k] = 0.0f;
#pragma unroll
  for (int r = 0; r < 4; ++r) {
    int p = lane + 64 * r;
    if (p < NP) {
#pragma unroll
      for (int k = 0; k < 10; ++k) {
        float4 w4 = *(const float4*)(W2s + k * 784 + 4 * p);
        acc[k] += ev[4*r+0] * w4.x + ev[4*r+1] * w4.y +
                  ev[4*r+2] * w4.z + ev[4*r+3] * w4.w;
      }
    }
  }
#pragma unroll
  for (int k = 0; k < 10; ++k)
#pragma unroll
    for (int off = 32; off; off >>= 1) acc[k] += __shfl_xor(acc[k], off);

  if (!alive) return;
  float lg[10], mx = -1e30f;
#pragma unroll
  for (int k = 0; k < 10; ++k) { lg[k] = acc[k] + bias[k]; mx = fmaxf(mx, lg[k]); }
  float sm = 0.0f;
#pragma unroll
  for (int k = 0; k < 10; ++k) sm += __expf(lg[k] - mx);
  float lse = mx + __logf(sm);
  if (lane < 10) {
    float sel = lg[0];
#pragma unroll
    for (int k = 1; k < 10; ++k) sel = (lane == k) ? lg[k] : sel;
    out[(size_t)b * 10 + lane] = sel - lse;
  }
}

extern "C" void kernel_launch(void* const* d_in, const int* in_sizes, int n_in,
                              void* d_out, int out_size, void* d_ws, size_t ws_size,
                              hipStream_t stream) {
  const float* x  = (const float*)d_in[0];  // (B,1,28,28) f32
  const float* qp = (const float*)d_in[1];  // (6,) f32
  const float* W  = (const float*)d_in[2];  // (10,784) f32
  const float* bi = (const float*)d_in[3];  // (10,) f32
  float* out = (float*)d_out;               // (B,10) f32

  int Bsz = in_sizes[0] / 784;              // 4096

  int grid = (Bsz + 15) / 16;               // 256 blocks, 16 samples/block
  k_fused<<<grid, 1024, 0, stream>>>(x, qp, W, bi, out, Bsz);
}

// Round 11
// 101.143 us; speedup vs baseline: 5.1412x; 1.2028x over previous
//
#include <hip/hip_runtime.h>
#include <hip/hip_bf16.h>

// QuanvolutionGraphQLClassifier — f32 in/out. ONE kernel, 256 blocks x 1024
// (16 samples/block), per-block redundant adjacency fold (no cross-block sync
// — R7/R9 polling catastrophes; no small-grid producer — R2-R6 ~40us stall).
// R10 fix: fold was stalled on global W loads + byte-stride-198 LDS conflicts
// (SQ_LDS_BANK_CONFLICT=1.8M, VALUBusy 28%). Now: W staged in LDS; adjacency
// codes transposed/padded A[n*200+m] so the n-uniform fold reads coalesced
// bytes (4 lanes/word broadcast) and wave-uniform W rows; all 16 waves fold.
//
// Math (verified R4+): e_d = wA . H_d . wB per patch; codes c(m,n) in {0,1,2}
// from normalized sample-0 meas; W2[k][4m+d] = 0.5 * sum_n c(m,n) W[k][4n+d];
// logits = meas . W2^T + bias; log_softmax.

#define NP 196

__device__ __forceinline__ float quad3(const float* H, const float* wa,
                                       const float* wb) {
  return wa[0] * (H[0] * wb[0] + H[1] * wb[1] + H[2] * wb[2]) +
         wa[1] * (H[3] * wb[0] + H[4] * wb[1] + H[5] * wb[2]) +
         wa[2] * (H[6] * wb[0] + H[7] * wb[1] + H[8] * wb[2]);
}

// Builds the full H[36] (A: 0..17, B: 18..35) — wave-uniform, all regs.
__device__ __forceinline__ void build_H_all(const float* __restrict__ qp,
                                            float* __restrict__ H) {
  float qc[6], qs[6];
#pragma unroll
  for (int i = 0; i < 6; ++i) __sincosf(0.5f * qp[i], &qs[i], &qc[i]);
#pragma unroll
  for (int sub = 0; sub < 2; ++sub) {
    float Mr[4][4] = {}, Mi[4][4] = {};
    if (sub == 0) {
      // U_A = RY(q4,w0) * CNOT01 * RY(q1,w1) * RX(q0,w0); index = 2*b0 + b1
      Mr[0][0] = Mr[1][1] = Mr[2][2] = Mr[3][3] = qc[0];  // RX(q0) on w0
      Mi[0][2] = Mi[2][0] = Mi[1][3] = Mi[3][1] = -qs[0];
#pragma unroll
      for (int j = 0; j < 4; ++j) {  // RY(q1) on w1: rows (0,1),(2,3)
        float a, b;
        a = Mr[0][j]; b = Mr[1][j]; Mr[0][j] = qc[1]*a - qs[1]*b; Mr[1][j] = qs[1]*a + qc[1]*b;
        a = Mi[0][j]; b = Mi[1][j]; Mi[0][j] = qc[1]*a - qs[1]*b; Mi[1][j] = qs[1]*a + qc[1]*b;
        a = Mr[2][j]; b = Mr[3][j]; Mr[2][j] = qc[1]*a - qs[1]*b; Mr[3][j] = qs[1]*a + qc[1]*b;
        a = Mi[2][j]; b = Mi[3][j]; Mi[2][j] = qc[1]*a - qs[1]*b; Mi[3][j] = qs[1]*a + qc[1]*b;
      }
#pragma unroll
      for (int j = 0; j < 4; ++j) {  // CNOT(0,1): swap rows 2,3
        float r = Mr[2][j]; Mr[2][j] = Mr[3][j]; Mr[3][j] = r;
        float q = Mi[2][j]; Mi[2][j] = Mi[3][j]; Mi[3][j] = q;
      }
#pragma unroll
      for (int j = 0; j < 4; ++j) {  // RY(q4) on w0: rows (0,2),(1,3)
        float a, b;
        a = Mr[0][j]; b = Mr[2][j]; Mr[0][j] = qc[4]*a - qs[4]*b; Mr[2][j] = qs[4]*a + qc[4]*b;
        a = Mi[0][j]; b = Mi[2][j]; Mi[0][j] = qc[4]*a - qs[4]*b; Mi[2][j] = qs[4]*a + qc[4]*b;
        a = Mr[1][j]; b = Mr[3][j]; Mr[1][j] = qc[4]*a - qs[4]*b; Mr[3][j] = qs[4]*a + qc[4]*b;
        a = Mi[1][j]; b = Mi[3][j]; Mi[1][j] = qc[4]*a - qs[4]*b; Mi[3][j] = qs[4]*a + qc[4]*b;
      }
    } else {
      // U_B = RZ(q5,w3) * CNOT23 * RX(q3,w3) * RZ(q2,w2); index = 2*b2 + b3
      Mr[0][0] = Mr[1][1] = Mr[2][2] = Mr[3][3] = qc[2];  // RZ(q2) on w2
      Mi[0][0] = Mi[1][1] = -qs[2]; Mi[2][2] = Mi[3][3] = qs[2];
#pragma unroll
      for (int j = 0; j < 4; ++j) {  // RX(q3) on w3: rows (0,1),(2,3)
        float ra, ia, rb, ib;
        ra = Mr[0][j]; ia = Mi[0][j]; rb = Mr[1][j]; ib = Mi[1][j];
        Mr[0][j] = qc[3]*ra + qs[3]*ib;  Mi[0][j] = qc[3]*ia - qs[3]*rb;
        Mr[1][j] = qc[3]*rb + qs[3]*ia;  Mi[1][j] = qc[3]*ib - qs[3]*ra;
        ra = Mr[2][j]; ia = Mi[2][j]; rb = Mr[3][j]; ib = Mi[3][j];
        Mr[2][j] = qc[3]*ra + qs[3]*ib;  Mi[2][j] = qc[3]*ia - qs[3]*rb;
        Mr[3][j] = qc[3]*rb + qs[3]*ia;  Mi[3][j] = qc[3]*ib - qs[3]*ra;
      }
#pragma unroll
      for (int j = 0; j < 4; ++j) {  // CNOT(2,3): swap rows 2,3
        float r = Mr[2][j]; Mr[2][j] = Mr[3][j]; Mr[3][j] = r;
        float q = Mi[2][j]; Mi[2][j] = Mi[3][j]; Mi[3][j] = q;
      }
#pragma unroll
      for (int r = 0; r < 4; ++r) {  // RZ(q5) on w3: rows 0,2 *(c5-is5); 1,3 *(c5+is5)
        float sg = (r & 1) ? 1.0f : -1.0f;
#pragma unroll
        for (int j = 0; j < 4; ++j) {
          float re = Mr[r][j], im = Mi[r][j];
          Mr[r][j] = qc[5] * re - sg * qs[5] * im;
          Mi[r][j] = qc[5] * im + sg * qs[5] * re;
        }
      }
    }
    // G_d[j][k] = sum_i sigma_i (Re U_ij Re U_ik + Im U_ij Im U_ik)
#pragma unroll
    for (int d = 0; d < 2; ++d) {
      float G[4][4];
#pragma unroll
      for (int j = 0; j < 4; ++j)
#pragma unroll
        for (int k = 0; k < 4; ++k) {
          float g = 0.0f;
#pragma unroll
          for (int i = 0; i < 4; ++i) {
            float sg = (d == 0) ? ((i < 2) ? 1.f : -1.f)
                                : (((i & 1) == 0) ? 1.f : -1.f);
            g += sg * (Mr[i][j] * Mr[i][k] + Mi[i][j] * Mi[i][k]);
          }
          G[j][k] = g;
        }
      float* Hd = H + sub * 18 + d * 9;
      Hd[0] = G[0][0];       Hd[1] = 2.f * G[0][1];               Hd[2] = G[1][1];
      Hd[3] = 2.f * G[0][2]; Hd[4] = 2.f * (G[0][3] + G[1][2]);   Hd[5] = 2.f * G[1][3];
      Hd[6] = G[2][2];       Hd[7] = 2.f * G[2][3];               Hd[8] = G[3][3];
    }
  }
}

// Pauli-Z expectations of patch p of image xb, via the H bilinear forms.
__device__ __forceinline__ void meas_patch(const float* __restrict__ xb, int p,
                                           const float* __restrict__ H,
                                           float* e) {
  int i = p / 14, j = p - 14 * i;
  float2 top = *(const float2*)(xb + 56 * i + 2 * j);
  float2 bot = *(const float2*)(xb + 56 * i + 28 + 2 * j);
  float c0, s0, c1, s1, c2, s2, c3, s3;
  __sincosf(0.5f * top.x, &s0, &c0);
  __sincosf(0.5f * top.y, &s1, &c1);
  __sincosf(0.5f * bot.x, &s2, &c2);
  __sincosf(0.5f * bot.y, &s3, &c3);
  float wA0[3] = {c0 * c0, c0 * s0, s0 * s0};
  float wA1[3] = {c1 * c1, c1 * s1, s1 * s1};
  float wB0[3] = {c2 * c2, c2 * s2, s2 * s2};
  float wB1[3] = {c3 * c3, c3 * s3, s3 * s3};
  e[0] = quad3(H, wA0, wA1);
  e[1] = quad3(H + 9, wA0, wA1);
  e[2] = quad3(H + 18, wB0, wB1);
  e[3] = quad3(H + 27, wB0, wB1);
}

__global__ __launch_bounds__(1024, 1) void k_fused(
    const float* __restrict__ x, const float* __restrict__ qp,
    const float* __restrict__ W, const float* __restrict__ bias,
    float* __restrict__ out, int Bsz) {
  __shared__ float Hl[36];
  __shared__ float4 us[NP];                // sample-0 meas, normalized (3.1 KB)
  __shared__ unsigned char A[NP * 200];    // codes {0,1,2}, TRANSPOSED:
                                           //   A[n*200+m]  (39.2 KB)
  __shared__ float Wl[10 * 784];           // W staged (31.4 KB)
  __shared__ float W2s[10 * 784];          // folded weights (31.4 KB)
  int t = threadIdx.x, wv = t >> 6, lane = t & 63;
  int b = blockIdx.x * 16 + wv;
  bool alive = (b < Bsz);

  // ---- stage W -> LDS (all threads) ----
  for (int i = t; i < 1960; i += 1024)
    ((float4*)Wl)[i] = ((const float4*)W)[i];

  // ---- wave 0: H -> LDS, sample-0 normalized meas -> LDS ----
  if (wv == 0) {
    float H0[36];
    build_H_all(qp, H0);
    if (lane == 0) {
#pragma unroll
      for (int i = 0; i < 36; ++i) Hl[i] = H0[i];  // constant reg indices
    }
#pragma unroll
    for (int r = 0; r < 4; ++r) {
      int p = lane + 64 * r;
      if (p < NP) {
        float e[4];
        meas_patch(x, p, H0, e);
        float n = sqrtf(e[0]*e[0] + e[1]*e[1] + e[2]*e[2] + e[3]*e[3]) + 1e-12f;
        float rn = 1.0f / n;
        us[p] = make_float4(e[0]*rn, e[1]*rn, e[2]*rn, e[3]*rn);
      }
    }
  }
  __syncthreads();

  // ---- phase A: classify -> packed codes, 4 per dword write ----
  // task o: n = o/49, j = o%49 -> codes for m = 4j..4j+3 at A[n*200+4j]
  for (int o = t; o < NP * 49; o += 1024) {
    int n = o / 49, j = o - n * 49;
    float4 un = us[n];
    unsigned int pk = 0;
#pragma unroll
    for (int i = 0; i < 4; ++i) {
      float4 um = us[4 * j + i];
      float dot = um.x*un.x + um.y*un.y + um.z*un.z + um.w*un.w;
      unsigned int c = (dot >= 0.9f) ? 2u : ((dot >= 0.5f) ? 1u : 0u);
      pk |= c << (8 * i);
    }
    *(unsigned int*)(A + n * 200 + 4 * j) = pk;
  }
  __syncthreads();

  // ---- phase B: fold. 40 tasks (k,round) over 16 waves; lane owns m. ----
  for (int T = wv; T < 40; T += 16) {
    int k = T >> 2, round = T & 3;
    int m = round * 64 + lane;
    if (m < NP) {
      float a0 = 0.f, a1 = 0.f, a2 = 0.f, a3 = 0.f;
      const float* Wk = Wl + k * 784;
      const unsigned char* An = A + m;
#pragma unroll 4
      for (int n = 0; n < NP; ++n) {
        float w = (float)An[n * 200];        // coalesced bytes across lanes
        float4 w4 = *(const float4*)(Wk + 4 * n);  // wave-uniform -> broadcast
        a0 += w * w4.x; a1 += w * w4.y; a2 += w * w4.z; a3 += w * w4.w;
      }
      float* dst = W2s + k * 784 + 4 * m;
      dst[0] = 0.5f * a0; dst[1] = 0.5f * a1;
      dst[2] = 0.5f * a2; dst[3] = 0.5f * a3;
    }
  }
  __syncthreads();

  // ---- per wave: own-sample meas (regs), W2 dot, reduce, log_softmax ----
  float H[36];
#pragma unroll
  for (int i = 0; i < 36; ++i) H[i] = Hl[i];
  const float* xb = x + (size_t)(alive ? b : 0) * 784;
  float ev[16];
#pragma unroll
  for (int r = 0; r < 4; ++r) {
    int p = lane + 64 * r;
    if (p < NP) {
      float e[4];
      meas_patch(xb, p, H, e);
      ev[4*r+0] = e[0]; ev[4*r+1] = e[1]; ev[4*r+2] = e[2]; ev[4*r+3] = e[3];
    } else {
      ev[4*r+0] = ev[4*r+1] = ev[4*r+2] = ev[4*r+3] = 0.f;
    }
  }
  float acc[10];
#pragma unroll
  for (int k = 0; k < 10; ++k) acc[k] = 0.0f;
#pragma unroll
  for (int r = 0; r < 4; ++r) {
    int p = lane + 64 * r;
    if (p < NP) {
#pragma unroll
      for (int k = 0; k < 10; ++k) {
        float4 w4 = *(const float4*)(W2s + k * 784 + 4 * p);
        acc[k] += ev[4*r+0] * w4.x + ev[4*r+1] * w4.y +
                  ev[4*r+2] * w4.z + ev[4*r+3] * w4.w;
      }
    }
  }
#pragma unroll
  for (int k = 0; k < 10; ++k)
#pragma unroll
    for (int off = 32; off; off >>= 1) acc[k] += __shfl_xor(acc[k], off);

  if (!alive) return;
  float lg[10], mx = -1e30f;
#pragma unroll
  for (int k = 0; k < 10; ++k) { lg[k] = acc[k] + bias[k]; mx = fmaxf(mx, lg[k]); }
  float sm = 0.0f;
#pragma unroll
  for (int k = 0; k < 10; ++k) sm += __expf(lg[k] - mx);
  float lse = mx + __logf(sm);
  if (lane < 10) {
    float sel = lg[0];
#pragma unroll
    for (int k = 1; k < 10; ++k) sel = (lane == k) ? lg[k] : sel;
    out[(size_t)b * 10 + lane] = sel - lse;
  }
}

extern "C" void kernel_launch(void* const* d_in, const int* in_sizes, int n_in,
                              void* d_out, int out_size, void* d_ws, size_t ws_size,
                              hipStream_t stream) {
  const float* x  = (const float*)d_in[0];  // (B,1,28,28) f32
  const float* qp = (const float*)d_in[1];  // (6,) f32
  const float* W  = (const float*)d_in[2];  // (10,784) f32
  const float* bi = (const float*)d_in[3];  // (10,) f32
  float* out = (float*)d_out;               // (B,10) f32

  int Bsz = in_sizes[0] / 784;              // 4096

  int grid = (Bsz + 15) / 16;               // 256 blocks, 16 samples/block
  k_fused<<<grid, 1024, 0, stream>>>(x, qp, W, bi, out, Bsz);
}